// Round 1
// baseline (113.245 us; speedup 1.0000x reference)
//
#include <hip/hip_runtime.h>

// NNLoss: min over 5x5 shifted neighborhoods of channel-summed L1 distance,
// then global mean. B=16, C=3, H=W=512, fp32.

#define PADV (-10000.0f)

constexpr int Bn = 16, Cn = 3, Hn = 512, Wn = 512;
constexpr int NH = 5, NW = 5;
constexpr int STRIPS_PER_ROW = Wn / 4;                 // 128
constexpr long PLANE = (long)Hn * Wn;                  // 262144
constexpr int NSTRIP = Bn * Hn * STRIPS_PER_ROW;       // 1,048,576
constexpr int BLOCK = 256;
constexpr int NBLOCKS = NSTRIP / BLOCK;                // 4096

__global__ __launch_bounds__(BLOCK) void nnloss_main(
    const float* __restrict__ pred, const float* __restrict__ gt,
    float* __restrict__ partial) {
  const int t = blockIdx.x * BLOCK + threadIdx.x;      // strip id
  const int w0 = (t & (STRIPS_PER_ROW - 1)) * 4;
  const int rem = t >> 7;                              // / STRIPS_PER_ROW
  const int h = rem & (Hn - 1);
  const int b = rem >> 9;                              // / Hn

  const float* pb = pred + (long)b * Cn * PLANE + (long)h * Wn + w0;
  const float* gb = gt + (long)b * Cn * PLANE;

  // predicted: 4 consecutive pixels, 3 channels
  float p[Cn][4];
#pragma unroll
  for (int c = 0; c < Cn; ++c) {
    const float4 v = *(const float4*)(pb + (long)c * PLANE);
    p[c][0] = v.x; p[c][1] = v.y; p[c][2] = v.z; p[c][3] = v.w;
  }

  float m[4] = {3.0e38f, 3.0e38f, 3.0e38f, 3.0e38f};

  const bool interior = (h >= 2) && (h <= Hn - 3) && (w0 >= 4) && (w0 <= Wn - 8);
  if (interior) {
#pragma unroll
    for (int di = 0; di < NH; ++di) {
      float s[NW][4];
#pragma unroll
      for (int dj = 0; dj < NW; ++dj) {
        s[dj][0] = 0.f; s[dj][1] = 0.f; s[dj][2] = 0.f; s[dj][3] = 0.f;
      }
#pragma unroll
      for (int c = 0; c < Cn; ++c) {
        const float* row = gb + (long)c * PLANE + (long)(h + di - 2) * Wn + (w0 - 4);
        const float4 a = *(const float4*)(row);
        const float4 bq = *(const float4*)(row + 4);
        const float4 cq = *(const float4*)(row + 8);
        const float g[12] = {a.x, a.y, a.z, a.w, bq.x, bq.y, bq.z, bq.w,
                             cq.x, cq.y, cq.z, cq.w};
#pragma unroll
        for (int dj = 0; dj < NW; ++dj)
#pragma unroll
          for (int q = 0; q < 4; ++q)
            s[dj][q] += fabsf(g[q + dj + 2] - p[c][q]);
      }
#pragma unroll
      for (int dj = 0; dj < NW; ++dj)
#pragma unroll
        for (int q = 0; q < 4; ++q)
          m[q] = fminf(m[q], s[dj][q]);
    }
  } else {
    // boundary strips: guarded element loads, PAD_VAL outside
#pragma unroll
    for (int di = 0; di < NH; ++di) {
      const int hr = h + di - 2;
      const bool rok = (hr >= 0) && (hr < Hn);
      const int hrc = rok ? hr : 0;
      float s[NW][4];
#pragma unroll
      for (int dj = 0; dj < NW; ++dj) {
        s[dj][0] = 0.f; s[dj][1] = 0.f; s[dj][2] = 0.f; s[dj][3] = 0.f;
      }
#pragma unroll
      for (int c = 0; c < Cn; ++c) {
        const float* row = gb + (long)c * PLANE + (long)hrc * Wn;
        float g[12];
#pragma unroll
        for (int k = 0; k < 12; ++k) {
          const int col = w0 - 4 + k;
          g[k] = (rok && col >= 0 && col < Wn) ? row[col] : PADV;
        }
#pragma unroll
        for (int dj = 0; dj < NW; ++dj)
#pragma unroll
          for (int q = 0; q < 4; ++q)
            s[dj][q] += fabsf(g[q + dj + 2] - p[c][q]);
      }
#pragma unroll
      for (int dj = 0; dj < NW; ++dj)
#pragma unroll
        for (int q = 0; q < 4; ++q)
          m[q] = fminf(m[q], s[dj][q]);
    }
  }

  float v = (m[0] + m[1]) + (m[2] + m[3]);

  // wave64 reduce, then cross-wave via LDS
#pragma unroll
  for (int off = 32; off > 0; off >>= 1) v += __shfl_down(v, off, 64);
  __shared__ float wsum[BLOCK / 64];
  const int lane = threadIdx.x & 63;
  const int wid = threadIdx.x >> 6;
  if (lane == 0) wsum[wid] = v;
  __syncthreads();
  if (threadIdx.x == 0)
    partial[blockIdx.x] = (wsum[0] + wsum[1]) + (wsum[2] + wsum[3]);
}

__global__ __launch_bounds__(256) void nnloss_reduce(
    const float* __restrict__ partial, float* __restrict__ out) {
  double acc = 0.0;
  for (int i = threadIdx.x; i < NBLOCKS; i += 256) acc += (double)partial[i];
#pragma unroll
  for (int off = 32; off > 0; off >>= 1) acc += __shfl_down(acc, off, 64);
  __shared__ double sd[4];
  const int lane = threadIdx.x & 63;
  const int wid = threadIdx.x >> 6;
  if (lane == 0) sd[wid] = acc;
  __syncthreads();
  if (threadIdx.x == 0) {
    const double tot = (sd[0] + sd[1]) + (sd[2] + sd[3]);
    out[0] = (float)(tot / ((double)Bn * Hn * Wn));
  }
}

extern "C" void kernel_launch(void* const* d_in, const int* in_sizes, int n_in,
                              void* d_out, int out_size, void* d_ws, size_t ws_size,
                              hipStream_t stream) {
  const float* pred = (const float*)d_in[0];
  const float* gt = (const float*)d_in[1];
  // d_in[2], d_in[3] are nh=5, nw=5 (hard-coded)
  float* out = (float*)d_out;
  float* partial = (float*)d_ws;   // 4096 floats = 16 KB

  nnloss_main<<<NBLOCKS, BLOCK, 0, stream>>>(pred, gt, partial);
  nnloss_reduce<<<1, 256, 0, stream>>>(partial, out);
}

// Round 2
// 38.656 us; speedup vs baseline: 2.9296x; 2.9296x over previous
//
#include <hip/hip_runtime.h>

// NNLoss: min over 5x5 shifted neighborhoods of channel-summed L1 distance,
// then global mean. B=16, C=3, H=W=512, fp32.
// Strategy: LDS-stage gt halo tile per block (with PAD_VAL fill -> uniform
// compute, no boundary branch), compute 4 px/thread from LDS.

#define PADV (-10000.0f)

constexpr int Bn = 16, Cn = 3, Hn = 512, Wn = 512;
constexpr long PLANE = (long)Hn * Wn;                  // 262144

constexpr int TW = 64, TH = 16;                        // output tile per block
constexpr int GW = TW + 4;                             // 68 staged cols (w0-2 .. w0+65)
constexpr int GH = TH + 4;                             // 20 staged rows (h0-2 .. h0+17)
constexpr int BLOCK = 256;
constexpr int TILES_W = Wn / TW;                       // 8
constexpr int TILES_H = Hn / TH;                       // 32
constexpr int NBLOCKS = Bn * TILES_H * TILES_W;        // 4096

__global__ __launch_bounds__(BLOCK, 4) void nnloss_main(
    const float* __restrict__ pred, const float* __restrict__ gt,
    float* __restrict__ partial) {
  const int bid = blockIdx.x;
  const int tw = bid & (TILES_W - 1);
  const int th = (bid >> 3) & (TILES_H - 1);
  const int b = bid >> 8;
  const int w0 = tw * TW;
  const int h0 = th * TH;

  __shared__ __align__(16) float tile[Cn][GH][GW];     // 16,320 B

  const float* gb = gt + (long)b * Cn * PLANE;

  // ---- stage gt halo tile (coalesced, PAD_VAL outside image) ----
#pragma unroll
  for (int c = 0; c < Cn; ++c) {
    const float* gp = gb + (long)c * PLANE;
    for (int idx = threadIdx.x; idx < GH * GW; idx += BLOCK) {
      const int r = idx / GW;
      const int col = idx - r * GW;
      const int gh = h0 - 2 + r;
      const int gw = w0 - 2 + col;
      const bool ok = (gh >= 0) && (gh < Hn) && (gw >= 0) && (gw < Wn);
      tile[c][r][col] = ok ? gp[(long)gh * Wn + gw] : PADV;
    }
  }
  __syncthreads();

  // ---- compute: each thread owns 4 consecutive px ----
  const int tx = threadIdx.x & 15;                     // w strip within tile
  const int ty = threadIdx.x >> 4;                     // row within tile

  float p[Cn][4];
  const float* pb =
      pred + (long)b * Cn * PLANE + (long)(h0 + ty) * Wn + (w0 + 4 * tx);
#pragma unroll
  for (int c = 0; c < Cn; ++c) {
    const float4 v = *(const float4*)(pb + (long)c * PLANE);
    p[c][0] = v.x; p[c][1] = v.y; p[c][2] = v.z; p[c][3] = v.w;
  }

  float m[4] = {3.0e38f, 3.0e38f, 3.0e38f, 3.0e38f};

#pragma unroll
  for (int di = 0; di < 5; ++di) {
    float s[5][4];
#pragma unroll
    for (int dj = 0; dj < 5; ++dj) {
      s[dj][0] = 0.f; s[dj][1] = 0.f; s[dj][2] = 0.f; s[dj][3] = 0.f;
    }
#pragma unroll
    for (int c = 0; c < Cn; ++c) {
      // needed LDS cols: 4*tx + q + dj, (q+dj) in [0,7] -> two aligned float4
      const float4 a = *(const float4*)&tile[c][ty + di][4 * tx];
      const float4 bq = *(const float4*)&tile[c][ty + di][4 * tx + 4];
      const float g[8] = {a.x, a.y, a.z, a.w, bq.x, bq.y, bq.z, bq.w};
#pragma unroll
      for (int dj = 0; dj < 5; ++dj)
#pragma unroll
        for (int q = 0; q < 4; ++q)
          s[dj][q] += fabsf(g[q + dj] - p[c][q]);
    }
#pragma unroll
    for (int dj = 0; dj < 5; ++dj)
#pragma unroll
      for (int q = 0; q < 4; ++q)
        m[q] = fminf(m[q], s[dj][q]);
  }

  float v = (m[0] + m[1]) + (m[2] + m[3]);

  // ---- block reduction ----
#pragma unroll
  for (int off = 32; off > 0; off >>= 1) v += __shfl_down(v, off, 64);
  __shared__ float wsum[BLOCK / 64];
  const int lane = threadIdx.x & 63;
  const int wid = threadIdx.x >> 6;
  if (lane == 0) wsum[wid] = v;
  __syncthreads();
  if (threadIdx.x == 0)
    partial[blockIdx.x] = (wsum[0] + wsum[1]) + (wsum[2] + wsum[3]);
}

__global__ __launch_bounds__(256) void nnloss_reduce(
    const float* __restrict__ partial, float* __restrict__ out) {
  double acc = 0.0;
  for (int i = threadIdx.x; i < NBLOCKS; i += 256) acc += (double)partial[i];
#pragma unroll
  for (int off = 32; off > 0; off >>= 1) acc += __shfl_down(acc, off, 64);
  __shared__ double sd[4];
  const int lane = threadIdx.x & 63;
  const int wid = threadIdx.x >> 6;
  if (lane == 0) sd[wid] = acc;
  __syncthreads();
  if (threadIdx.x == 0) {
    const double tot = (sd[0] + sd[1]) + (sd[2] + sd[3]);
    out[0] = (float)(tot / ((double)Bn * Hn * Wn));
  }
}

extern "C" void kernel_launch(void* const* d_in, const int* in_sizes, int n_in,
                              void* d_out, int out_size, void* d_ws, size_t ws_size,
                              hipStream_t stream) {
  const float* pred = (const float*)d_in[0];
  const float* gt = (const float*)d_in[1];
  // d_in[2], d_in[3] are nh=5, nw=5 (hard-coded)
  float* out = (float*)d_out;
  float* partial = (float*)d_ws;  // 4096 floats = 16 KB

  nnloss_main<<<NBLOCKS, BLOCK, 0, stream>>>(pred, gt, partial);
  nnloss_reduce<<<1, 256, 0, stream>>>(partial, out);
}